// Round 2
// 463.726 us; speedup vs baseline: 1.0050x; 1.0050x over previous
//
#include <hip/hip_runtime.h>

// Activation1d (BigVGAN-style anti-aliased snake-beta), fp32.
// x: (B=16, C=512, T=8192). 2x upsample (K=12) -> snake -> 2x downsample.
//
// Index math (verified against jax conv_general_dilated semantics):
//   up[2s]   = 2*(f1*x(s+2)+f3*x(s+1)+f5*x(s)+f7*x(s-1)+f9*x(s-2)+f11*x(s-3))
//   up[2s+1] = 2*(f0*x(s+3)+f2*x(s+2)+f4*x(s+1)+f6*x(s)+f8*x(s-1)+f10*x(s-2))
//   act[t] = up[t] + (1/(exp(beta)+1e-9)) * sin(up[t]*exp(alpha))^2
//   out[n] = sum_k df[k] * act[clamp(2n+k-5, 0, 2T-1)]
//
// Packed-fp32 revision (VOP3P v_pk_fma_f32/v_pk_mul_f32). Pairing act
// (j=2p, j=2p+1): the t-odd phase at xi=p+5 and t-even phase at xi=p+6
// multiply the SAME x element per tap:
//   upp[p] = sum_m (2uf[2m], 2uf[2m+1]) * splat(xr[p+8-m])   (6 pk_fma, op_sel bcast)
// Down-conv consumes only ALIGNED act pairs:
//   o[d] = sum_m dot(dfp[m], a2[d+m])                        (6 pk_fma + h-add)
// sin folded to raw v_sin_f32 (1/2pi pre-multiplied into exp(alpha)).
// NT hints on output stores via native ext_vector float4 (HIP float4 class is
// rejected by __builtin_nontemporal_store).

#define T_LEN 8192
#define C_CH  512
#define B_N   16
#define W     8
#define BLOCK 256

typedef float f2 __attribute__((ext_vector_type(2)));
typedef float f4 __attribute__((ext_vector_type(4)));

// ---- packed-fp32 helpers (VOP3P, gfx90a+) ----
__device__ __forceinline__ f2 pk_mul(f2 a, f2 b) {
    f2 d; asm("v_pk_mul_f32 %0, %1, %2" : "=v"(d) : "v"(a), "v"(b)); return d;
}
__device__ __forceinline__ f2 pk_mul_bx(f2 a, f2 b) { // a * splat(b.x)
    f2 d; asm("v_pk_mul_f32 %0, %1, %2 op_sel:[0,0] op_sel_hi:[1,0]" : "=v"(d) : "v"(a), "v"(b)); return d;
}
__device__ __forceinline__ f2 pk_mul_by(f2 a, f2 b) { // a * splat(b.y)
    f2 d; asm("v_pk_mul_f32 %0, %1, %2 op_sel:[0,1] op_sel_hi:[1,1]" : "=v"(d) : "v"(a), "v"(b)); return d;
}
__device__ __forceinline__ void pk_fma(f2& acc, f2 a, f2 b) { // acc += a*b
    asm("v_pk_fma_f32 %0, %1, %2, %0" : "+v"(acc) : "v"(a), "v"(b));
}
__device__ __forceinline__ void pk_fma_bx(f2& acc, f2 a, f2 b) { // acc += a*splat(b.x)
    asm("v_pk_fma_f32 %0, %1, %2, %0 op_sel:[0,0,0] op_sel_hi:[1,0,1]" : "+v"(acc) : "v"(a), "v"(b));
}
__device__ __forceinline__ void pk_fma_by(f2& acc, f2 a, f2 b) { // acc += a*splat(b.y)
    asm("v_pk_fma_f32 %0, %1, %2, %0 op_sel:[0,1,0] op_sel_hi:[1,1,1]" : "+v"(acc) : "v"(a), "v"(b));
}
__device__ __forceinline__ float hw_sin(float x_rev) { // sin(2*pi*x_rev)
    float r; asm("v_sin_f32 %0, %1" : "=v"(r) : "v"(x_rev)); return r;
}

__global__ __launch_bounds__(BLOCK) void act1d_kernel(
    const float* __restrict__ x,
    const float* __restrict__ uf_g,
    const float* __restrict__ df_g,
    const float* __restrict__ alpha,
    const float* __restrict__ beta,
    float* __restrict__ out)
{
    const int T = T_LEN;
    const int bid = blockIdx.x;
    const int row = bid >> 2;          // b*C + c   (4 blocks per row: 4*256*8 = 8192)
    const int chunk = bid & 3;
    const int c = row & (C_CH - 1);
    const int nb = chunk * (BLOCK * W) + (int)threadIdx.x * W;
    const long rowoff = (long)row * T;
    const float* xrow = x + rowoff;

    // filters as pairs: ufp[m] = (2uf[2m], 2uf[2m+1]), dfp[m] = (df[2m], df[2m+1])
    f2 ufp[6], dfp[6];
    const f2* ufv = (const f2*)uf_g;
    const f2* dfv = (const f2*)df_g;
#pragma unroll
    for (int m = 0; m < 6; ++m) {
        f2 u = ufv[m];
        ufp[m].x = 2.0f * u.x; ufp[m].y = 2.0f * u.y;
        dfp[m] = dfv[m];
    }

    const float ea_r = __expf(alpha[c]) * 0.15915494309189535f;  // fold 1/2pi for v_sin
    const float invb = 1.0f / (__expf(beta[c]) + 1e-9f);
    f2 eap; eap.x = ea_r; eap.y = ea_r;
    f2 ibp; ibp.x = invb; ibp.y = invb;

    f2 a2[13];   // a2[p] = (act[2*nb-5+2p], act[2*nb-5+2p+1])

    const bool interior = (nb >= 8) && (nb + 16 <= T);
    if (interior) {
        // xx[q] = (x[nb-8+2q], x[nb-8+2q+1]); loaded as 6x float4 (32B-aligned)
        f2 xx[12];
        const f4* xv4 = (const f4*)(xrow + nb - 8);
#pragma unroll
        for (int k = 0; k < 6; ++k) {
            f4 v = xv4[k];
            xx[2*k].x   = v.x; xx[2*k].y   = v.y;
            xx[2*k+1].x = v.z; xx[2*k+1].y = v.w;
        }
#pragma unroll
        for (int p = 0; p < 13; ++p) {
            // up pair: taps m=0..5 multiply xr[p+8-m] on BOTH lanes
            f2 u;
            {
                const int w = p + 8;
                if (w & 1) u = pk_mul_by(ufp[0], xx[w >> 1]);
                else       u = pk_mul_bx(ufp[0], xx[w >> 1]);
            }
#pragma unroll
            for (int m = 1; m < 6; ++m) {
                const int w = p + 8 - m;
                if (w & 1) pk_fma_by(u, ufp[m], xx[w >> 1]);
                else       pk_fma_bx(u, ufp[m], xx[w >> 1]);
            }
            // snake: a = up + invb * sin(up*ea)^2
            f2 s = pk_mul(u, eap);
            f2 sv; sv.x = hw_sin(s.x); sv.y = hw_sin(s.y);
            f2 t = pk_mul(sv, ibp);
            f2 av = u;
            pk_fma(av, t, sv);
            a2[p] = av;
        }
    } else {
        // edge threads (nb==0 or nb==T-8): generic path, per-tap clamped global
        // loads (L2-resident; only 2 threads per row ever take this).
#pragma unroll
        for (int j = 0; j < 26; ++j) {
            int t = 2*nb - 5 + j;
            t = min(max(t, 0), 2*T - 1);
            const int s = t >> 1;
            const int par = t & 1;
            float xv7[7];
#pragma unroll
            for (int m = 0; m < 7; ++m) {
                int g = s - 3 + m;
                g = min(max(g, 0), T - 1);
                xv7[m] = xrow[g];
            }
            // xv7[3+d] == x[clamp(s+d)]
            const float upo = ufp[0].x*xv7[6] + ufp[1].x*xv7[5] + ufp[2].x*xv7[4]
                            + ufp[3].x*xv7[3] + ufp[4].x*xv7[2] + ufp[5].x*xv7[1];
            const float upe = ufp[0].y*xv7[5] + ufp[1].y*xv7[4] + ufp[2].y*xv7[3]
                            + ufp[3].y*xv7[2] + ufp[4].y*xv7[1] + ufp[5].y*xv7[0];
            const float up = par ? upo : upe;
            const float sv = hw_sin(up * ea_r);
            const float aj = fmaf(invb * sv, sv, up);
            if (j & 1) a2[j >> 1].y = aj; else a2[j >> 1].x = aj;
        }
    }

    // down-conv: o[d] = sum_k df[k]*a[2d+k] = sum_m dot(dfp[m], a2[d+m])
    float o[W];
#pragma unroll
    for (int d = 0; d < W; ++d) {
        f2 acc = pk_mul(dfp[0], a2[d]);
#pragma unroll
        for (int m = 1; m < 6; ++m) pk_fma(acc, dfp[m], a2[d + m]);
        o[d] = acc.x + acc.y;
    }
    f4* ov = (f4*)(out + rowoff + nb);
    f4 o0; o0.x = o[0]; o0.y = o[1]; o0.z = o[2]; o0.w = o[3];
    f4 o1; o1.x = o[4]; o1.y = o[5]; o1.z = o[6]; o1.w = o[7];
    __builtin_nontemporal_store(o0, ov);
    __builtin_nontemporal_store(o1, ov + 1);
}

extern "C" void kernel_launch(void* const* d_in, const int* in_sizes, int n_in,
                              void* d_out, int out_size, void* d_ws, size_t ws_size,
                              hipStream_t stream) {
    const float* x  = (const float*)d_in[0];
    const float* uf = (const float*)d_in[1];
    const float* df = (const float*)d_in[2];
    const float* al = (const float*)d_in[3];
    const float* be = (const float*)d_in[4];
    float* outp = (float*)d_out;

    const int grid = B_N * C_CH * (T_LEN / (BLOCK * W));  // 32768
    act1d_kernel<<<grid, BLOCK, 0, stream>>>(x, uf, df, al, be, outp);
}

// Round 3
// 443.698 us; speedup vs baseline: 1.0503x; 1.0451x over previous
//
#include <hip/hip_runtime.h>

// Activation1d (BigVGAN-style anti-aliased snake-beta), fp32.
// x: (B=16, C=512, T=8192). 2x upsample (K=12) -> snake -> 2x downsample.
//
// Index math (verified against jax conv_general_dilated semantics):
//   up[2s]   = 2*(f1*x(s+2)+f3*x(s+1)+f5*x(s)+f7*x(s-1)+f9*x(s-2)+f11*x(s-3))
//   up[2s+1] = 2*(f0*x(s+3)+f2*x(s+2)+f4*x(s+1)+f6*x(s)+f8*x(s-1)+f10*x(s-2))
//   act[t] = up[t] + (1/(exp(beta)+1e-9)) * sin(up[t]*exp(alpha))^2
//   out[n] = sum_k df[k] * act[clamp(2n+k-5, 0, 2T-1)]
//
// Rev 3: persistent-row + software-pipelined register prefetch.
//   - grid = B*C = 8192 blocks; one block owns one row; each thread does
//     ITERS=4 chunks of W=8 outputs.
//   - double-buffered x registers: while computing chunk it, the 6
//     global_load_dwordx4 for chunk it+1 are in flight (no LDS, no barriers
//     -> compiler emits counted vmcnt, no drain).
//   - all loads use a row-clamped 32B-aligned base so edge threads issue the
//     same vector loads (contents unused there; generic clamped path).
//   - packed-fp32 (v_pk_fma_f32 + op_sel broadcast) compute from round 2.
//   - plain stores (NT stores grew WRITE_SIZE 262->278MB; reverted).

#define T_LEN 8192
#define C_CH  512
#define B_N   16
#define W     8
#define BLOCK 256
#define ITERS 4   // BLOCK*W*ITERS == T_LEN

typedef float f2 __attribute__((ext_vector_type(2)));
typedef float f4 __attribute__((ext_vector_type(4)));

// ---- packed-fp32 helpers (VOP3P) ----
__device__ __forceinline__ f2 pk_mul(f2 a, f2 b) {
    f2 d; asm("v_pk_mul_f32 %0, %1, %2" : "=v"(d) : "v"(a), "v"(b)); return d;
}
__device__ __forceinline__ f2 pk_mul_bx(f2 a, f2 b) { // a * splat(b.x)
    f2 d; asm("v_pk_mul_f32 %0, %1, %2 op_sel:[0,0] op_sel_hi:[1,0]" : "=v"(d) : "v"(a), "v"(b)); return d;
}
__device__ __forceinline__ f2 pk_mul_by(f2 a, f2 b) { // a * splat(b.y)
    f2 d; asm("v_pk_mul_f32 %0, %1, %2 op_sel:[0,1] op_sel_hi:[1,1]" : "=v"(d) : "v"(a), "v"(b)); return d;
}
__device__ __forceinline__ void pk_fma(f2& acc, f2 a, f2 b) { // acc += a*b
    asm("v_pk_fma_f32 %0, %1, %2, %0" : "+v"(acc) : "v"(a), "v"(b));
}
__device__ __forceinline__ void pk_fma_bx(f2& acc, f2 a, f2 b) { // acc += a*splat(b.x)
    asm("v_pk_fma_f32 %0, %1, %2, %0 op_sel:[0,0,0] op_sel_hi:[1,0,1]" : "+v"(acc) : "v"(a), "v"(b));
}
__device__ __forceinline__ void pk_fma_by(f2& acc, f2 a, f2 b) { // acc += a*splat(b.y)
    asm("v_pk_fma_f32 %0, %1, %2, %0 op_sel:[0,1,0] op_sel_hi:[1,1,1]" : "+v"(acc) : "v"(a), "v"(b));
}
__device__ __forceinline__ float hw_sin(float x_rev) { // sin(2*pi*x_rev)
    float r; asm("v_sin_f32 %0, %1" : "=v"(r) : "v"(x_rev)); return r;
}

__global__ __launch_bounds__(BLOCK) void act1d_kernel(
    const float* __restrict__ x,
    const float* __restrict__ uf_g,
    const float* __restrict__ df_g,
    const float* __restrict__ alpha,
    const float* __restrict__ beta,
    float* __restrict__ out)
{
    const int T = T_LEN;
    const int row = blockIdx.x;            // b*C + c
    const int c = row & (C_CH - 1);
    const long rowoff = (long)row * T;
    const float* xrow = x + rowoff;
    float* orow = out + rowoff;
    const int t0 = (int)threadIdx.x * W;   // base offset within a chunk

    // filters as pairs: ufp[m] = (2uf[2m], 2uf[2m+1]), dfp[m] = (df[2m], df[2m+1])
    f2 ufp[6], dfp[6];
    const f2* ufv = (const f2*)uf_g;
    const f2* dfv = (const f2*)df_g;
#pragma unroll
    for (int m = 0; m < 6; ++m) {
        f2 u = ufv[m];
        ufp[m].x = 2.0f * u.x; ufp[m].y = 2.0f * u.y;
        dfp[m] = dfv[m];
    }

    const float ea_r = __expf(alpha[c]) * 0.15915494309189535f;  // fold 1/2pi for v_sin
    const float invb = 1.0f / (__expf(beta[c]) + 1e-9f);
    f2 eap; eap.x = ea_r; eap.y = ea_r;
    f2 ibp; ibp.x = invb; ibp.y = invb;

    // double-buffered x registers: xb[buf][q] = (x[nb-8+2q], x[nb-8+2q+1])
    f2 xb[2][12];

    // prologue: issue loads for chunk 0
    {
        const int nb = t0;
        const float* lb = xrow + min(max(nb - 8, 0), T - 24);  // 32B-aligned clamp
        const f4* p4 = (const f4*)lb;
#pragma unroll
        for (int k = 0; k < 6; ++k) {
            f4 v = p4[k];
            xb[0][2*k].x   = v.x; xb[0][2*k].y   = v.y;
            xb[0][2*k+1].x = v.z; xb[0][2*k+1].y = v.w;
        }
    }

#pragma unroll
    for (int it = 0; it < ITERS; ++it) {
        const int cur = it & 1;
        const int nxt = cur ^ 1;
        const int nb = it * (BLOCK * W) + t0;

        // prefetch next chunk (loads in flight across this iteration's compute)
        if (it + 1 < ITERS) {
            const int nb2 = (it + 1) * (BLOCK * W) + t0;
            const float* lb = xrow + min(max(nb2 - 8, 0), T - 24);
            const f4* p4 = (const f4*)lb;
#pragma unroll
            for (int k = 0; k < 6; ++k) {
                f4 v = p4[k];
                xb[nxt][2*k].x   = v.x; xb[nxt][2*k].y   = v.y;
                xb[nxt][2*k+1].x = v.z; xb[nxt][2*k+1].y = v.w;
            }
        }

        f2 a2[13];   // a2[p] = (act[2*nb-5+2p], act[2*nb-5+2p+1])

        // middle iterations are compile-time provably interior
        const bool interior = (it > 0 && it < ITERS - 1) || ((nb >= 8) && (nb + 16 <= T));
        if (interior) {
#pragma unroll
            for (int p = 0; p < 13; ++p) {
                // up pair: taps m=0..5 multiply xr[p+8-m] on BOTH lanes
                f2 u;
                {
                    const int w = p + 8;
                    if (w & 1) u = pk_mul_by(ufp[0], xb[cur][w >> 1]);
                    else       u = pk_mul_bx(ufp[0], xb[cur][w >> 1]);
                }
#pragma unroll
                for (int m = 1; m < 6; ++m) {
                    const int w = p + 8 - m;
                    if (w & 1) pk_fma_by(u, ufp[m], xb[cur][w >> 1]);
                    else       pk_fma_bx(u, ufp[m], xb[cur][w >> 1]);
                }
                // snake: a = up + invb * sin(up*ea)^2
                f2 s = pk_mul(u, eap);
                f2 sv; sv.x = hw_sin(s.x); sv.y = hw_sin(s.y);
                f2 tt = pk_mul(sv, ibp);
                f2 av = u;
                pk_fma(av, tt, sv);
                a2[p] = av;
            }
        } else {
            // edge threads (nb==0 or nb==T-8): generic per-tap clamped loads
            // (L2-resident; 2 threads per row total).
#pragma unroll
            for (int j = 0; j < 26; ++j) {
                int t = 2*nb - 5 + j;
                t = min(max(t, 0), 2*T - 1);
                const int s = t >> 1;
                const int par = t & 1;
                float xv7[7];
#pragma unroll
                for (int m = 0; m < 7; ++m) {
                    int g = s - 3 + m;
                    g = min(max(g, 0), T - 1);
                    xv7[m] = xrow[g];
                }
                // xv7[3+d] == x[clamp(s+d)]
                const float upo = ufp[0].x*xv7[6] + ufp[1].x*xv7[5] + ufp[2].x*xv7[4]
                                + ufp[3].x*xv7[3] + ufp[4].x*xv7[2] + ufp[5].x*xv7[1];
                const float upe = ufp[0].y*xv7[5] + ufp[1].y*xv7[4] + ufp[2].y*xv7[3]
                                + ufp[3].y*xv7[2] + ufp[4].y*xv7[1] + ufp[5].y*xv7[0];
                const float up = par ? upo : upe;
                const float sv = hw_sin(up * ea_r);
                const float aj = fmaf(invb * sv, sv, up);
                if (j & 1) a2[j >> 1].y = aj; else a2[j >> 1].x = aj;
            }
        }

        // down-conv: o[d] = sum_k df[k]*a[2d+k] = sum_m dot(dfp[m], a2[d+m])
        float o[W];
#pragma unroll
        for (int d = 0; d < W; ++d) {
            f2 acc = pk_mul(dfp[0], a2[d]);
#pragma unroll
            for (int m = 1; m < 6; ++m) pk_fma(acc, dfp[m], a2[d + m]);
            o[d] = acc.x + acc.y;
        }
        f4* ov = (f4*)(orow + nb);
        f4 o0; o0.x = o[0]; o0.y = o[1]; o0.z = o[2]; o0.w = o[3];
        f4 o1; o1.x = o[4]; o1.y = o[5]; o1.z = o[6]; o1.w = o[7];
        ov[0] = o0;
        ov[1] = o1;
    }
}

extern "C" void kernel_launch(void* const* d_in, const int* in_sizes, int n_in,
                              void* d_out, int out_size, void* d_ws, size_t ws_size,
                              hipStream_t stream) {
    const float* x  = (const float*)d_in[0];
    const float* uf = (const float*)d_in[1];
    const float* df = (const float*)d_in[2];
    const float* al = (const float*)d_in[3];
    const float* be = (const float*)d_in[4];
    float* outp = (float*)d_out;

    const int grid = B_N * C_CH;   // 8192 rows, one block per row
    act1d_kernel<<<grid, BLOCK, 0, stream>>>(x, uf, df, al, be, outp);
}